// Round 2
// baseline (2914.794 us; speedup 1.0000x reference)
//
#include <hip/hip_runtime.h>
#include <stdint.h>

// Problem constants
#define BATCH 4096
#define DIMD  256
#define DIMH  1024

// ---------------- threefry2x32 (JAX-compatible, 20 rounds) ----------------
__host__ __device__ static inline uint32_t rotl32(uint32_t v, int r) {
    return (v << r) | (v >> (32 - r));
}

__host__ __device__ static inline void tf2x32(uint32_t k0, uint32_t k1,
                                              uint32_t c0, uint32_t c1,
                                              uint32_t& o0, uint32_t& o1) {
    uint32_t ks0 = k0, ks1 = k1, ks2 = k0 ^ k1 ^ 0x1BD11BDAu;
    uint32_t x0 = c0 + ks0, x1 = c1 + ks1;
#define TF_R4(a, b, c, d)                                   \
    x0 += x1; x1 = rotl32(x1, a); x1 ^= x0;                 \
    x0 += x1; x1 = rotl32(x1, b); x1 ^= x0;                 \
    x0 += x1; x1 = rotl32(x1, c); x1 ^= x0;                 \
    x0 += x1; x1 = rotl32(x1, d); x1 ^= x0;
    TF_R4(13, 15, 26, 6)  x0 += ks1; x1 += ks2 + 1u;
    TF_R4(17, 29, 16, 24) x0 += ks2; x1 += ks0 + 2u;
    TF_R4(13, 15, 26, 6)  x0 += ks0; x1 += ks1 + 3u;
    TF_R4(17, 29, 16, 24) x0 += ks1; x1 += ks2 + 4u;
    TF_R4(13, 15, 26, 6)  x0 += ks2; x1 += ks0 + 5u;
#undef TF_R4
    o0 = x0; o1 = x1;
}

// ---------------- K1: h = tanh((x + c*fz_prev) @ W1z + t*W1[256] + b1) ----
// M=4096, N=1024, K=256. BM=BN=64, BK=16, 256 threads, 4x4 per thread.
__global__ __launch_bounds__(256) void k_pre_tanh(
    const float* __restrict__ x, const float* __restrict__ fzprev, float cmul,
    const float* __restrict__ W1, const float* __restrict__ b1, float tval,
    float* __restrict__ h_out)
{
    __shared__ float As[64][17];
    __shared__ float Bs[16][64];
    const int tid = threadIdx.x;
    const int tx = tid & 15, ty = tid >> 4;
    const int b0 = blockIdx.x * 64;
    const int k0 = blockIdx.y * 64;
    float acc[4][4] = {};
    const bool use_prev = (cmul != 0.0f);

    for (int d0 = 0; d0 < DIMD; d0 += 16) {
#pragma unroll
        for (int q = 0; q < 4; ++q) {
            int e = tid + q * 256;
            int r = e >> 4, dd = e & 15;
            int gi = (b0 + r) * DIMD + d0 + dd;
            float v = x[gi];
            if (use_prev) v += cmul * fzprev[gi];
            As[r][dd] = v;
        }
#pragma unroll
        for (int q = 0; q < 4; ++q) {
            int e = tid + q * 256;
            int dd = e >> 6, kk = e & 63;
            Bs[dd][kk] = W1[(d0 + dd) * DIMH + k0 + kk];
        }
        __syncthreads();
#pragma unroll
        for (int dd = 0; dd < 16; ++dd) {
            float a[4], bb[4];
#pragma unroll
            for (int i = 0; i < 4; ++i) a[i] = As[ty * 4 + i][dd];
#pragma unroll
            for (int j = 0; j < 4; ++j) bb[j] = Bs[dd][tx * 4 + j];
#pragma unroll
            for (int i = 0; i < 4; ++i)
#pragma unroll
                for (int j = 0; j < 4; ++j) acc[i][j] = fmaf(a[i], bb[j], acc[i][j]);
        }
        __syncthreads();
    }
#pragma unroll
    for (int j = 0; j < 4; ++j) {
        int k = k0 + tx * 4 + j;
        float add = tval * W1[DIMD * DIMH + k] + b1[k];  // t-row (index 256) + bias
#pragma unroll
        for (int i = 0; i < 4; ++i) {
            int b = b0 + ty * 4 + i;
            h_out[b * DIMH + k] = tanhf(acc[i][j] + add);
        }
    }
}

// ---------------- K2: fz = h @ W2 + b2 ------------------------------------
// M=4096, N=256, K=1024. Same tiling.
__global__ __launch_bounds__(256) void k_fz(
    const float* __restrict__ h, const float* __restrict__ W2,
    const float* __restrict__ b2, float* __restrict__ fz)
{
    __shared__ float As[64][17];
    __shared__ float Bs[16][64];
    const int tid = threadIdx.x;
    const int tx = tid & 15, ty = tid >> 4;
    const int b0 = blockIdx.x * 64;
    const int k0 = blockIdx.y * 64;
    float acc[4][4] = {};

    for (int d0 = 0; d0 < DIMH; d0 += 16) {
#pragma unroll
        for (int q = 0; q < 4; ++q) {
            int e = tid + q * 256;
            int r = e >> 4, dd = e & 15;
            As[r][dd] = h[(b0 + r) * DIMH + d0 + dd];
        }
#pragma unroll
        for (int q = 0; q < 4; ++q) {
            int e = tid + q * 256;
            int dd = e >> 6, kk = e & 63;
            Bs[dd][kk] = W2[(d0 + dd) * DIMD + k0 + kk];
        }
        __syncthreads();
#pragma unroll
        for (int dd = 0; dd < 16; ++dd) {
            float a[4], bb[4];
#pragma unroll
            for (int i = 0; i < 4; ++i) a[i] = As[ty * 4 + i][dd];
#pragma unroll
            for (int j = 0; j < 4; ++j) bb[j] = Bs[dd][tx * 4 + j];
#pragma unroll
            for (int i = 0; i < 4; ++i)
#pragma unroll
                for (int j = 0; j < 4; ++j) acc[i][j] = fmaf(a[i], bb[j], acc[i][j]);
        }
        __syncthreads();
    }
#pragma unroll
    for (int j = 0; j < 4; ++j) {
        int k = k0 + tx * 4 + j;
        float bias = b2[k];
#pragma unroll
        for (int i = 0; i < 4; ++i)
            fz[(b0 + ty * 4 + i) * DIMD + k] = acc[i][j] + bias;
    }
}

// ---------------- W2 transpose: W2T[d][k] = W2[k][d] ----------------------
__global__ __launch_bounds__(256) void k_transpose(
    const float* __restrict__ W2, float* __restrict__ W2T)
{
    __shared__ float tile[32][33];
    const int bx = blockIdx.x;  // along k: 1024/32 = 32
    const int by = blockIdx.y;  // along d: 256/32 = 8
    const int tx = threadIdx.x, ty = threadIdx.y;  // (32, 8)
#pragma unroll
    for (int i = 0; i < 4; ++i)
        tile[ty + i * 8][tx] = W2[(bx * 32 + ty + i * 8) * DIMD + by * 32 + tx];
    __syncthreads();
#pragma unroll
    for (int i = 0; i < 4; ++i)
        W2T[(by * 32 + ty + i * 8) * DIMH + bx * 32 + tx] = tile[tx][ty + i * 8];
}

// ---------------- K3: Hutchinson probe contributions ----------------------
// div[b] += 0.1 * sum_k (e@W1z)_k * (1-h^2)_k * (e@W2^T)_k  per probe
// Block: 256 threads, 8 batch rows of one probe. Thread t owns k = t+256m.
// Rademacher bits per JAX partitionable threefry (default since JAX 0.4.30):
//   bits[j] = (y0 ^ y1) of threefry2x32(k2, (0, j)), j = flat index into
//   (10, 4096, 256); e = (bits & 1) ? +1 : -1.
__global__ __launch_bounds__(256) void k_div(
    const float* __restrict__ W1, const float* __restrict__ W2T,
    const float* __restrict__ h, float* __restrict__ divacc,
    uint32_t key0, uint32_t key1)
{
    __shared__ float e_l[8][256];
    const int t = threadIdx.x;
    const int b0 = blockIdx.x * 8;
    const int probe = blockIdx.y;

#pragma unroll
    for (int g = 0; g < 8; ++g) {
        uint32_t j = (uint32_t)((probe * BATCH + b0 + g) * DIMD + t);
        uint32_t y0, y1;
        tf2x32(key0, key1, 0u, j, y0, y1);
        uint32_t w = y0 ^ y1;
        e_l[g][t] = (w & 1u) ? 1.0f : -1.0f;
    }
    __syncthreads();

    float u[4][8] = {};
    float v[4][8] = {};
    for (int d = 0; d < DIMD; ++d) {
        float w1v[4], w2v[4];
#pragma unroll
        for (int m = 0; m < 4; ++m) w1v[m] = W1[d * DIMH + t + m * 256];
#pragma unroll
        for (int m = 0; m < 4; ++m) w2v[m] = W2T[d * DIMH + t + m * 256];
#pragma unroll
        for (int g = 0; g < 8; ++g) {
            float e = e_l[g][d];
#pragma unroll
            for (int m = 0; m < 4; ++m) {
                u[m][g] = fmaf(e, w1v[m], u[m][g]);
                v[m][g] = fmaf(e, w2v[m], v[m][g]);
            }
        }
    }

#pragma unroll
    for (int g = 0; g < 8; ++g) {
        int b = b0 + g;
        float part = 0.0f;
#pragma unroll
        for (int m = 0; m < 4; ++m) {
            float hv = h[b * DIMH + t + m * 256];
            float s = 1.0f - hv * hv;
            part += u[m][g] * s * v[m][g];
        }
        for (int off = 32; off > 0; off >>= 1)
            part += __shfl_down(part, off, 64);
        if ((t & 63) == 0) atomicAdd(&divacc[b], part * 0.1f);
    }
}

// ---------------- K4: RK4 combine + output --------------------------------
__global__ __launch_bounds__(256) void k_out(
    const float* __restrict__ x, const float* __restrict__ fz,
    const float* __restrict__ divacc, float* __restrict__ out)
{
    const int idx = blockIdx.x * 256 + threadIdx.x;
    const int TOT = BATCH * (DIMD + 1);
    if (idx >= TOT) return;
    const int b = idx / (DIMD + 1);
    const int c = idx - b * (DIMD + 1);
    const float sixth = 1.0f / 6.0f;
    if (c < DIMD) {
        float xv = x[b * DIMD + c];
        int o = b * DIMD + c;
        float f1 = fz[o];
        float f2 = fz[BATCH * DIMD + o];
        float f3 = fz[2 * BATCH * DIMD + o];
        float f4 = fz[3 * BATCH * DIMD + o];
        out[idx] = xv;
        out[TOT + idx] = xv + (f1 + 2.0f * f2 + 2.0f * f3 + f4) * sixth;
    } else {
        float d1 = divacc[b];
        float d2 = divacc[BATCH + b];
        float d3 = divacc[2 * BATCH + b];
        float d4 = divacc[3 * BATCH + b];
        out[idx] = 0.0f;
        out[TOT + idx] = -(d1 + 2.0f * d2 + 2.0f * d3 + d4) * sixth;
    }
}

// ---------------- launch ---------------------------------------------------
extern "C" void kernel_launch(void* const* d_in, const int* in_sizes, int n_in,
                              void* d_out, int out_size, void* d_ws, size_t ws_size,
                              hipStream_t stream) {
    const float* x  = (const float*)d_in[0];
    const float* W1 = (const float*)d_in[1];
    const float* b1 = (const float*)d_in[2];
    const float* W2 = (const float*)d_in[3];
    const float* b2 = (const float*)d_in[4];
    float* out = (float*)d_out;

    char* ws = (char*)d_ws;
    float* hbuf = (float*)(ws);                              // 4096*1024*4 = 16 MiB
    float* fz   = (float*)(ws + 16777216);                   // 4*4096*256*4 = 16 MiB
    float* w2t  = (float*)(ws + 33554432);                   // 256*1024*4 = 1 MiB
    float* dv   = (float*)(ws + 34603008);                   // 4*4096*4 = 64 KiB

    // Host-side threefry key derivation (partitionable semantics, the JAX
    // default since 0.4.30):
    //   ekey = key(42) -> (0,42)
    //   fk_i = threefry2x32((0,42), (0,i))          [fold_in]
    //   split(fk_i) -> subkey m = threefry2x32(fk_i, (0,m)); randint uses k2
    //   (m=1) as the lower_bits key; span=2 => bit = lower_bits & 1.
    uint32_t keys[4][2];
    for (uint32_t i = 0; i < 4; ++i) {
        uint32_t f0, f1, g0, g1;
        tf2x32(0u, 42u, 0u, i, f0, f1);
        tf2x32(f0, f1, 0u, 1u, g0, g1);
        keys[i][0] = g0;
        keys[i][1] = g1;
    }

    hipMemsetAsync(dv, 0, 4 * BATCH * sizeof(float), stream);

    dim3 tb(32, 8);
    k_transpose<<<dim3(32, 8), tb, 0, stream>>>(W2, w2t);

    const float tvals[4] = {0.0f, 0.5f, 0.5f, 1.0f};
    const float cvals[4] = {0.0f, 0.5f, 0.5f, 1.0f};
    for (int s = 0; s < 4; ++s) {
        const float* fzprev = (s == 0) ? x : (fz + (size_t)(s - 1) * BATCH * DIMD);
        k_pre_tanh<<<dim3(64, 16), 256, 0, stream>>>(x, fzprev, cvals[s], W1, b1,
                                                     tvals[s], hbuf);
        k_fz<<<dim3(64, 4), 256, 0, stream>>>(hbuf, W2, b2,
                                              fz + (size_t)s * BATCH * DIMD);
        k_div<<<dim3(BATCH / 8, 10), 256, 0, stream>>>(W1, w2t, hbuf,
                                                       dv + (size_t)s * BATCH,
                                                       keys[s][0], keys[s][1]);
    }
    int tot = BATCH * (DIMD + 1);
    k_out<<<(tot + 255) / 256, 256, 0, stream>>>(x, fz, dv, out);
}

// Round 3
// 990.253 us; speedup vs baseline: 2.9435x; 2.9435x over previous
//
#include <hip/hip_runtime.h>
#include <stdint.h>

// Problem constants
#define BATCH 4096
#define DIMD  256
#define DIMH  1024
#define EPAD  264   // E tile row stride in bf16 elems (256 + 8 pad -> 2-way LDS aliasing only)

typedef __attribute__((ext_vector_type(8))) short short8;
typedef __attribute__((ext_vector_type(4))) float float4v;

// ---------------- threefry2x32 (JAX-compatible, 20 rounds) ----------------
__host__ __device__ static inline uint32_t rotl32(uint32_t v, int r) {
    return (v << r) | (v >> (32 - r));
}

__host__ __device__ static inline void tf2x32(uint32_t k0, uint32_t k1,
                                              uint32_t c0, uint32_t c1,
                                              uint32_t& o0, uint32_t& o1) {
    uint32_t ks0 = k0, ks1 = k1, ks2 = k0 ^ k1 ^ 0x1BD11BDAu;
    uint32_t x0 = c0 + ks0, x1 = c1 + ks1;
#define TF_R4(a, b, c, d)                                   \
    x0 += x1; x1 = rotl32(x1, a); x1 ^= x0;                 \
    x0 += x1; x1 = rotl32(x1, b); x1 ^= x0;                 \
    x0 += x1; x1 = rotl32(x1, c); x1 ^= x0;                 \
    x0 += x1; x1 = rotl32(x1, d); x1 ^= x0;
    TF_R4(13, 15, 26, 6)  x0 += ks1; x1 += ks2 + 1u;
    TF_R4(17, 29, 16, 24) x0 += ks2; x1 += ks0 + 2u;
    TF_R4(13, 15, 26, 6)  x0 += ks0; x1 += ks1 + 3u;
    TF_R4(17, 29, 16, 24) x0 += ks1; x1 += ks2 + 4u;
    TF_R4(13, 15, 26, 6)  x0 += ks2; x1 += ks0 + 5u;
#undef TF_R4
    o0 = x0; o1 = x1;
}

// float -> bf16 (round-to-nearest-even), bit pattern in a short
__device__ static inline short f2bf(float f) {
    uint32_t u = __float_as_uint(f);
    uint32_t r = (u + 0x7FFFu + ((u >> 16) & 1u)) >> 16;
    return (short)r;
}

// ---------------- K1: h = tanh((x + c*fz_prev) @ W1z + t*W1[256] + b1) ----
// M=4096, N=1024, K=256. BM=BN=64, BK=16, 256 threads, 4x4 per thread.
__global__ __launch_bounds__(256) void k_pre_tanh(
    const float* __restrict__ x, const float* __restrict__ fzprev, float cmul,
    const float* __restrict__ W1, const float* __restrict__ b1, float tval,
    float* __restrict__ h_out)
{
    __shared__ float As[64][17];
    __shared__ float Bs[16][64];
    const int tid = threadIdx.x;
    const int tx = tid & 15, ty = tid >> 4;
    const int b0 = blockIdx.x * 64;
    const int k0 = blockIdx.y * 64;
    float acc[4][4] = {};
    const bool use_prev = (cmul != 0.0f);

    for (int d0 = 0; d0 < DIMD; d0 += 16) {
#pragma unroll
        for (int q = 0; q < 4; ++q) {
            int e = tid + q * 256;
            int r = e >> 4, dd = e & 15;
            int gi = (b0 + r) * DIMD + d0 + dd;
            float v = x[gi];
            if (use_prev) v += cmul * fzprev[gi];
            As[r][dd] = v;
        }
#pragma unroll
        for (int q = 0; q < 4; ++q) {
            int e = tid + q * 256;
            int dd = e >> 6, kk = e & 63;
            Bs[dd][kk] = W1[(d0 + dd) * DIMH + k0 + kk];
        }
        __syncthreads();
#pragma unroll
        for (int dd = 0; dd < 16; ++dd) {
            float a[4], bb[4];
#pragma unroll
            for (int i = 0; i < 4; ++i) a[i] = As[ty * 4 + i][dd];
#pragma unroll
            for (int j = 0; j < 4; ++j) bb[j] = Bs[dd][tx * 4 + j];
#pragma unroll
            for (int i = 0; i < 4; ++i)
#pragma unroll
                for (int j = 0; j < 4; ++j) acc[i][j] = fmaf(a[i], bb[j], acc[i][j]);
        }
        __syncthreads();
    }
#pragma unroll
    for (int j = 0; j < 4; ++j) {
        int k = k0 + tx * 4 + j;
        float add = tval * W1[DIMD * DIMH + k] + b1[k];  // t-row (index 256) + bias
#pragma unroll
        for (int i = 0; i < 4; ++i) {
            int b = b0 + ty * 4 + i;
            h_out[b * DIMH + k] = tanhf(acc[i][j] + add);
        }
    }
}

// ---------------- K2: fz = h @ W2 + b2 ------------------------------------
__global__ __launch_bounds__(256) void k_fz(
    const float* __restrict__ h, const float* __restrict__ W2,
    const float* __restrict__ b2, float* __restrict__ fz)
{
    __shared__ float As[64][17];
    __shared__ float Bs[16][64];
    const int tid = threadIdx.x;
    const int tx = tid & 15, ty = tid >> 4;
    const int b0 = blockIdx.x * 64;
    const int k0 = blockIdx.y * 64;
    float acc[4][4] = {};

    for (int d0 = 0; d0 < DIMH; d0 += 16) {
#pragma unroll
        for (int q = 0; q < 4; ++q) {
            int e = tid + q * 256;
            int r = e >> 4, dd = e & 15;
            As[r][dd] = h[(b0 + r) * DIMH + d0 + dd];
        }
#pragma unroll
        for (int q = 0; q < 4; ++q) {
            int e = tid + q * 256;
            int dd = e >> 6, kk = e & 63;
            Bs[dd][kk] = W2[(d0 + dd) * DIMD + k0 + kk];
        }
        __syncthreads();
#pragma unroll
        for (int dd = 0; dd < 16; ++dd) {
            float a[4], bb[4];
#pragma unroll
            for (int i = 0; i < 4; ++i) a[i] = As[ty * 4 + i][dd];
#pragma unroll
            for (int j = 0; j < 4; ++j) bb[j] = Bs[dd][tx * 4 + j];
#pragma unroll
            for (int i = 0; i < 4; ++i)
#pragma unroll
                for (int j = 0; j < 4; ++j) acc[i][j] = fmaf(a[i], bb[j], acc[i][j]);
        }
        __syncthreads();
    }
#pragma unroll
    for (int j = 0; j < 4; ++j) {
        int k = k0 + tx * 4 + j;
        float bias = b2[k];
#pragma unroll
        for (int i = 0; i < 4; ++i)
            fz[(b0 + ty * 4 + i) * DIMD + k] = acc[i][j] + bias;
    }
}

// ---------------- Prep: W1T[n][d] = bf16(W1[d][n])  (1024 x 256) ----------
__global__ __launch_bounds__(256) void k_w1t_bf16(
    const float* __restrict__ W1, short* __restrict__ W1T)
{
    __shared__ float tile[32][33];
    const int bx = blockIdx.x;  // n tiles: 1024/32 = 32
    const int by = blockIdx.y;  // d tiles: 256/32 = 8
    const int tx = threadIdx.x, ty = threadIdx.y;  // (32, 8)
#pragma unroll
    for (int i = 0; i < 4; ++i)
        tile[ty + i * 8][tx] = W1[(by * 32 + ty + i * 8) * DIMH + bx * 32 + tx];
    __syncthreads();
#pragma unroll
    for (int i = 0; i < 4; ++i)
        W1T[(bx * 32 + ty + i * 8) * DIMD + by * 32 + tx] = f2bf(tile[tx][ty + i * 8]);
}

// ---------------- Prep: W2B = bf16(W2)  (1024 x 256, straight convert) ----
__global__ __launch_bounds__(256) void k_w2b_bf16(
    const float* __restrict__ W2, short* __restrict__ W2B)
{
    int idx = blockIdx.x * 256 + threadIdx.x;
    if (idx < DIMH * DIMD) W2B[idx] = f2bf(W2[idx]);
}

// ---------------- K3: fused Hutchinson probe via MFMA ---------------------
// Block = (probe, 64-batch-tile). 256 threads = 4 waves.
// u[m][n] = sum_d E[m][d] * W1T[n][d],  v[m][n] = sum_d E[m][d] * W2B[n][d]
// div[b] += 0.1 * sum_n u * (1-h^2) * v
// Wave w owns n in [w*256, w*256+256) (16 n-subtiles of 16); inner loop over
// 4 M-subtiles with A-frags from LDS (B-frags loaded once per n-subtile).
__global__ __launch_bounds__(256) void k_div_mfma(
    const short* __restrict__ W1T, const short* __restrict__ W2B,
    const float* __restrict__ h, float* __restrict__ divacc,
    uint32_t key0, uint32_t key1)
{
    __shared__ short E[64 * EPAD];
    const int t = threadIdx.x;
    const int probe = blockIdx.x;      // fastest-varying -> 10 blocks share h slice in L2
    const int b0 = blockIdx.y * 64;

    // --- generate E tile (64 rows x 256 cols) of Rademacher +-1 (bf16) ---
    // JAX partitionable threefry: bit[j] = (y0^y1)&1 of tf(k2, (0, j)).
#pragma unroll 2
    for (int i = 0; i < 64; ++i) {
        uint32_t j = (uint32_t)((probe * BATCH + b0 + i) * DIMD + t);
        uint32_t y0, y1;
        tf2x32(key0, key1, 0u, j, y0, y1);
        E[i * EPAD + t] = ((y0 ^ y1) & 1u) ? (short)0x3F80 : (short)0xBF80u;
    }
    __syncthreads();

    const int wave = t >> 6;
    const int lane = t & 63;
    const int col = lane & 15;        // n (B/C col) and m (A row) lane index
    const int kq  = lane >> 4;        // k-quad for A/B frags; row-quad for C

    float rowacc[4][4];               // [m-subtile][reg] partial row sums
#pragma unroll
    for (int a = 0; a < 4; ++a)
#pragma unroll
        for (int r = 0; r < 4; ++r) rowacc[a][r] = 0.0f;

    for (int ns = 0; ns < 16; ++ns) {
        const int n = wave * 256 + ns * 16 + col;   // global col for this lane
        // B-fragments for u (W1T) and v (W2B): 8 k-steps each, 16B loads
        const short8* bu = (const short8*)&W1T[n * DIMD + kq * 8];
        const short8* bv = (const short8*)&W2B[n * DIMD + kq * 8];
        short8 bufr[8], bvfr[8];
#pragma unroll
        for (int ks = 0; ks < 8; ++ks) { bufr[ks] = bu[ks * 4]; bvfr[ks] = bv[ks * 4]; }

#pragma unroll
        for (int ms = 0; ms < 4; ++ms) {
            const short* arow = &E[(ms * 16 + col) * EPAD + kq * 8];
            float4v u = {0.f, 0.f, 0.f, 0.f}, v = {0.f, 0.f, 0.f, 0.f};
#pragma unroll
            for (int ks = 0; ks < 8; ++ks) {
                short8 af = *(const short8*)&arow[ks * 32];
                u = __builtin_amdgcn_mfma_f32_16x16x32_bf16(af, bufr[ks], u, 0, 0, 0);
                v = __builtin_amdgcn_mfma_f32_16x16x32_bf16(af, bvfr[ks], v, 0, 0, 0);
            }
            // C layout: col = lane&15, row = kq*4 + r  (verified m89/m91)
#pragma unroll
            for (int r = 0; r < 4; ++r) {
                float hv = h[(b0 + ms * 16 + kq * 4 + r) * DIMH + n];
                float s = 1.0f - hv * hv;
                rowacc[ms][r] += u[r] * s * v[r];
            }
        }
    }

    // reduce across the 16 lanes of each kq-group (cols), then atomics
#pragma unroll
    for (int ms = 0; ms < 4; ++ms) {
#pragma unroll
        for (int r = 0; r < 4; ++r) {
            float p = rowacc[ms][r];
            p += __shfl_xor(p, 1, 64);
            p += __shfl_xor(p, 2, 64);
            p += __shfl_xor(p, 4, 64);
            p += __shfl_xor(p, 8, 64);
            rowacc[ms][r] = p;
        }
    }
    if (col == 0) {
#pragma unroll
        for (int ms = 0; ms < 4; ++ms)
#pragma unroll
            for (int r = 0; r < 4; ++r)
                atomicAdd(&divacc[b0 + ms * 16 + kq * 4 + r], rowacc[ms][r] * 0.1f);
    }
}

// ---------------- K4: RK4 combine + output --------------------------------
__global__ __launch_bounds__(256) void k_out(
    const float* __restrict__ x, const float* __restrict__ fz,
    const float* __restrict__ divacc, float* __restrict__ out)
{
    const int idx = blockIdx.x * 256 + threadIdx.x;
    const int TOT = BATCH * (DIMD + 1);
    if (idx >= TOT) return;
    const int b = idx / (DIMD + 1);
    const int c = idx - b * (DIMD + 1);
    const float sixth = 1.0f / 6.0f;
    if (c < DIMD) {
        float xv = x[b * DIMD + c];
        int o = b * DIMD + c;
        float f1 = fz[o];
        float f2 = fz[BATCH * DIMD + o];
        float f3 = fz[2 * BATCH * DIMD + o];
        float f4 = fz[3 * BATCH * DIMD + o];
        out[idx] = xv;
        out[TOT + idx] = xv + (f1 + 2.0f * f2 + 2.0f * f3 + f4) * sixth;
    } else {
        float d1 = divacc[b];
        float d2 = divacc[BATCH + b];
        float d3 = divacc[2 * BATCH + b];
        float d4 = divacc[3 * BATCH + b];
        out[idx] = 0.0f;
        out[TOT + idx] = -(d1 + 2.0f * d2 + 2.0f * d3 + d4) * sixth;
    }
}

// ---------------- launch ---------------------------------------------------
extern "C" void kernel_launch(void* const* d_in, const int* in_sizes, int n_in,
                              void* d_out, int out_size, void* d_ws, size_t ws_size,
                              hipStream_t stream) {
    const float* x  = (const float*)d_in[0];
    const float* W1 = (const float*)d_in[1];
    const float* b1 = (const float*)d_in[2];
    const float* W2 = (const float*)d_in[3];
    const float* b2 = (const float*)d_in[4];
    float* out = (float*)d_out;

    char* ws = (char*)d_ws;
    float* hbuf = (float*)(ws);                    // 4096*1024*4 = 16 MiB
    float* fz   = (float*)(ws + 16777216);         // 4*4096*256*4 = 16 MiB
    short* w1t  = (short*)(ws + 33554432);         // 1024*256*2 = 512 KiB
    short* w2b  = (short*)(ws + 34078720);         // 1024*256*2 = 512 KiB
    float* dv   = (float*)(ws + 34603008);         // 4*4096*4 = 64 KiB

    // Host-side threefry key derivation (partitionable semantics):
    //   fk_i = tf((0,42),(0,i));  k2_i = tf(fk_i,(0,1))
    uint32_t keys[4][2];
    for (uint32_t i = 0; i < 4; ++i) {
        uint32_t f0, f1, g0, g1;
        tf2x32(0u, 42u, 0u, i, f0, f1);
        tf2x32(f0, f1, 0u, 1u, g0, g1);
        keys[i][0] = g0;
        keys[i][1] = g1;
    }

    hipMemsetAsync(dv, 0, 4 * BATCH * sizeof(float), stream);

    k_w1t_bf16<<<dim3(32, 8), dim3(32, 8), 0, stream>>>(W1, w1t);
    k_w2b_bf16<<<(DIMH * DIMD + 255) / 256, 256, 0, stream>>>(W2, w2b);

    const float tvals[4] = {0.0f, 0.5f, 0.5f, 1.0f};
    const float cvals[4] = {0.0f, 0.5f, 0.5f, 1.0f};
    for (int s = 0; s < 4; ++s) {
        const float* fzprev = (s == 0) ? x : (fz + (size_t)(s - 1) * BATCH * DIMD);
        k_pre_tanh<<<dim3(64, 16), 256, 0, stream>>>(x, fzprev, cvals[s], W1, b1,
                                                     tvals[s], hbuf);
        k_fz<<<dim3(64, 4), 256, 0, stream>>>(hbuf, W2, b2,
                                              fz + (size_t)s * BATCH * DIMD);
        k_div_mfma<<<dim3(10, BATCH / 64), 256, 0, stream>>>(w1t, w2b, hbuf,
                                                             dv + (size_t)s * BATCH,
                                                             keys[s][0], keys[s][1]);
    }
    int tot = BATCH * (DIMD + 1);
    k_out<<<(tot + 255) / 256, 256, 0, stream>>>(x, fz, dv, out);
}